// Round 4
// baseline (508.594 us; speedup 1.0000x reference)
//
#include <hip/hip_runtime.h>

#define M_PATCH 676
#define K_DIM   384
#define N_LIB   100000
#define BM      128
#define BN      128
#define NCH     782           // ceil(100000/128)
#define MTILES  6
#define M_PAD   (MTILES*BM)   // 768
#define N_PAD   (NCH*BN)      // 100096
#define NBG     (N_PAD/16)    // 6256 B 16-row groups
#define NAG     (M_PAD/16)    // 48 A 16-row groups
#define XCHUNK  98            // chunks per XCD (8*98 = 784 >= 782)
#define GRID_GEMM (8*XCHUNK*MTILES)   // 4704
#define NTOPB   1563          // ceil(100000/64)
#define NCAND   (NTOPB*3)
#define SH_LD   392           // padded LDS row stride (shorts) in cvt kernel
#define IMG     224
#define FMAP    26
#define KS      33
#define KHALF   16

typedef __attribute__((ext_vector_type(4))) float  f32x4;
typedef __attribute__((ext_vector_type(8))) short  short8;
typedef unsigned long long ull;

static __device__ __forceinline__ unsigned short f2bf(float f) {
  unsigned u = __float_as_uint(f);
  u = u + 0x7FFFu + ((u >> 16) & 1u);   // RNE; inputs finite
  return (unsigned short)(u >> 16);
}

static __device__ __forceinline__ ull shfl_xor_u64(ull v, int m) {
  unsigned lo = (unsigned)v, hi = (unsigned)(v >> 32);
  lo = __shfl_xor(lo, m, 64);
  hi = __shfl_xor(hi, m, 64);
  return ((ull)hi << 32) | lo;
}

static __device__ __forceinline__ ull umin64(ull a, ull b) { return a < b ? a : b; }
static __device__ __forceinline__ ull umax64(ull a, ull b) { return a > b ? a : b; }

// ---------------- K1: bf16 convert into MFMA-frag layout + norms -------------------------
// One block per 16-row group. Frag layout: tile (grp, kt) is 512 shorts at
// (grp*12+kt)*512; lane l holds M[grp*16 + (l&15)][kt*32 + (l>>4)*8 + j], j=0..7.
__global__ void pc_cvt_kernel(const float* __restrict__ patch, const float* __restrict__ lib,
                              float* __restrict__ y2, float* __restrict__ x2,
                              unsigned short* __restrict__ Afrag, unsigned short* __restrict__ Bfrag) {
  __shared__ unsigned short sh[16 * SH_LD];
  const int t = threadIdx.x;
  const int g = blockIdx.x;
  const bool isB = (g < NBG);
  const int gl = isB ? g : (g - NBG);
  const long r0 = (long)gl * 16;
  const float* src = isB ? lib : patch;
  const int nrows = isB ? N_LIB : M_PATCH;

  // step 1: coalesced fp32 read (16x96 float4), convert, store LDS
  #pragma unroll
  for (int i = 0; i < 6; ++i) {
    const int f = i * 256 + t;           // 0..1535
    const int r = f / 96, c = f - r * 96;
    const long gr = r0 + r;
    float4 v = make_float4(0.f, 0.f, 0.f, 0.f);
    if (gr < nrows) v = ((const float4*)(src + (size_t)gr * K_DIM))[c];
    *(ushort4*)&sh[r * SH_LD + c * 4] = make_ushort4(f2bf(v.x), f2bf(v.y), f2bf(v.z), f2bf(v.w));
  }
  __syncthreads();

  // step 2: row norms from the bf16 values (consistent with the MFMA dot)
  const int w = t >> 6, lane = t & 63;
  #pragma unroll
  for (int q = 0; q < 4; ++q) {
    const int r = w * 4 + q;
    float s = 0.f;
    #pragma unroll
    for (int j = 0; j < 6; ++j) {
      const float v = __uint_as_float((unsigned)sh[r * SH_LD + lane + 64 * j] << 16);
      s += v * v;
    }
    #pragma unroll
    for (int m = 1; m < 64; m <<= 1) s += __shfl_xor(s, m, 64);
    if (lane == 0) {
      const long gr = r0 + r;
      if (isB) y2[r0 + r] = (gr < N_LIB) ? s : __builtin_inff();
      else     x2[r0 + r] = s;
    }
  }

  // step 3: write frag-major tiles (coalesced 16B/lane stores)
  unsigned short* dst = isB ? (Bfrag + (size_t)gl * 12 * 512)
                            : (Afrag + (size_t)gl * 12 * 512);
  #pragma unroll
  for (int i = 0; i < 3; ++i) {
    const int c2 = i * 256 + t;          // 0..767
    const int kt = c2 >> 6, ln = c2 & 63;
    const int srow = ln & 15, koff = kt * 32 + (ln >> 4) * 8;
    const short8 vv = *(const short8*)&sh[srow * SH_LD + koff];
    *(short8*)&dst[(size_t)kt * 512 + ln * 8] = vv;
  }
}

// ---------------- K2: LDS-free MFMA GEMM (frag-layout global loads) + fused min ----------
__launch_bounds__(256, 3)
__global__ void pc_gemm_min_kernel(const unsigned short* __restrict__ Afrag,
                                   const unsigned short* __restrict__ Bfrag,
                                   const float* __restrict__ x2g, const float* __restrict__ y2g,
                                   ull* __restrict__ partial) {
  __shared__ float x2s[BM];
  __shared__ float y2s[BN];
  __shared__ ull red[BM * 2];

  const int l = blockIdx.x;
  const int xcd = l & 7, slot = l >> 3;
  const int chunk = xcd * XCHUNK + slot / MTILES;
  const int mtile = slot % MTILES;
  if (chunk >= NCH) return;

  const int t = threadIdx.x;
  const int m0 = mtile * BM;
  const int n0 = chunk * BN;
  const int wid = t >> 6, lane = t & 63;
  const int wm = wid >> 1, wn = wid & 1;

  if (t < BM) {
    const int gm = m0 + t;
    x2s[t] = (gm < M_PATCH) ? x2g[gm] : 0.f;
    y2s[t] = y2g[n0 + t];
  }

  const unsigned short* Ab = Afrag + (size_t)(mtile * 8 + wm * 4) * 12 * 512 + lane * 8;
  const unsigned short* Bb = Bfrag + (size_t)(chunk * 8 + wn * 4) * 12 * 512 + lane * 8;

  f32x4 acc[4][4];
  #pragma unroll
  for (int i = 0; i < 4; ++i)
    #pragma unroll
    for (int j = 0; j < 4; ++j) acc[i][j] = (f32x4){0.f, 0.f, 0.f, 0.f};

  #pragma unroll 2
  for (int ks = 0; ks < 12; ++ks) {
    short8 af[4], bf[4];
    #pragma unroll
    for (int mi = 0; mi < 4; ++mi)
      af[mi] = *(const short8*)(Ab + ((size_t)mi * 12 + ks) * 512);
    #pragma unroll
    for (int ni = 0; ni < 4; ++ni)
      bf[ni] = *(const short8*)(Bb + ((size_t)ni * 12 + ks) * 512);
    #pragma unroll
    for (int mi = 0; mi < 4; ++mi)
      #pragma unroll
      for (int ni = 0; ni < 4; ++ni)
        acc[mi][ni] = __builtin_amdgcn_mfma_f32_16x16x32_bf16(af[mi], bf[ni], acc[mi][ni], 0, 0, 0);
  }

  __syncthreads();   // x2s/y2s ready

  const int quad = lane >> 4, l15 = lane & 15;
  #pragma unroll
  for (int mi = 0; mi < 4; ++mi) {
    #pragma unroll
    for (int r = 0; r < 4; ++r) {
      const int row_l = wm * 64 + mi * 16 + quad * 4 + r;
      const float xs = x2s[row_l];
      ull kmin = ~0ull;
      #pragma unroll
      for (int ni = 0; ni < 4; ++ni) {
        const int col_l = wn * 64 + ni * 16 + l15;
        float d2 = xs + y2s[col_l] - 2.0f * acc[mi][ni][r];
        d2 = fmaxf(d2, 0.0f);
        const ull key = ((ull)__float_as_uint(d2) << 32) | (unsigned)(n0 + col_l);
        kmin = umin64(kmin, key);
      }
      #pragma unroll
      for (int off = 1; off < 16; off <<= 1) kmin = umin64(kmin, shfl_xor_u64(kmin, off));
      if (l15 == 0) red[row_l * 2 + wn] = kmin;
    }
  }
  __syncthreads();
  if (t < BM) {
    const ull k = umin64(red[t * 2], red[t * 2 + 1]);
    partial[(size_t)chunk * M_PAD + m0 + t] = k;   // coalesced 1KB per block
  }
}

// ---------------- K3: partial reduce (48 blocks) + last-block select ---------------------
// block = (mtile, chunk-group); 128 threads. Pad chunks 782/783 are memset to 0xFF.
__global__ void pc_reduce_kernel(const ull* __restrict__ partial, ull* __restrict__ stage1,
                                 float* __restrict__ minval, unsigned* __restrict__ minidx,
                                 unsigned* __restrict__ scal) {
  const int b = blockIdx.x, mt = b >> 3, gp = b & 7;
  const int t = threadIdx.x;           // 128
  const int c0 = gp * XCHUNK;
  ull k = ~0ull;
  #pragma unroll 7
  for (int i = 0; i < XCHUNK; ++i)
    k = umin64(k, partial[(size_t)(c0 + i) * M_PAD + mt * 128 + t]);
  stage1[(size_t)(mt * 128 + t) * 8 + gp] = k;
  __threadfence();
  __syncthreads();
  __shared__ unsigned rank_s;
  if (t == 0) rank_s = atomicAdd(&scal[8], 1u);
  __syncthreads();
  if (rank_s != 47) return;
  __threadfence();

  // last block: finalize minval/minidx + argmax
  ull best = 0ull;
  for (int m = t; m < M_PATCH; m += 128) {
    ull kk = ~0ull;
    #pragma unroll
    for (int g = 0; g < 8; ++g) kk = umin64(kk, stage1[(size_t)m * 8 + g]);
    const float d = sqrtf(fmaxf(__uint_as_float((unsigned)(kk >> 32)), 0.f));
    minval[m] = d;
    minidx[m] = (unsigned)kk;
    best = umax64(best, ((ull)__float_as_uint(d) << 32) | (0xFFFFFFFFu - (unsigned)m));
  }
  #pragma unroll
  for (int off = 1; off < 64; off <<= 1) best = umax64(best, shfl_xor_u64(best, off));
  __shared__ ull sh[2];
  if ((t & 63) == 0) sh[t >> 6] = best;
  __syncthreads();
  if (t == 0) {
    best = umax64(sh[0], sh[1]);
    const unsigned m = 0xFFFFFFFFu - (unsigned)best;
    scal[0] = m;                      // s_idx
    scal[1] = (unsigned)(best >> 32); // s_star bits
    scal[2] = minidx[m];              // m_star row
  }
}

// ---------------- K4: fp32 w_dist^2 + per-block top3 + last-block merge + score ----------
__global__ void pc_wdist_kernel(const float* __restrict__ patch, const float* __restrict__ lib,
                                unsigned* __restrict__ scal, ull* __restrict__ cand,
                                float* __restrict__ out) {
  __shared__ ull keys[64];
  const int t = threadIdx.x, w = t >> 6, lane = t & 63;
  const float2* ms = (const float2*)(lib + (size_t)scal[2] * K_DIM);
  float2 msv[3];
  #pragma unroll
  for (int j = 0; j < 3; ++j) msv[j] = ms[lane + 64 * j];
  const long r0 = (long)blockIdx.x * 64 + w * 16;
  for (int i = 0; i < 16; ++i) {
    const long r = r0 + i;
    ull key = ~0ull;
    if (r < N_LIB) {
      const float2* p = (const float2*)(lib + r * K_DIM);
      float s = 0.f;
      #pragma unroll
      for (int j = 0; j < 3; ++j) {
        const float2 v = p[lane + 64 * j];
        const float dx = v.x - msv[j].x, dy = v.y - msv[j].y;
        s += dx * dx + dy * dy;
      }
      #pragma unroll
      for (int m = 1; m < 64; m <<= 1) s += __shfl_xor(s, m, 64);
      key = ((ull)__float_as_uint(s) << 32) | (unsigned)r;  // squared: same ordering
    }
    if (lane == 0) keys[w * 16 + i] = key;
  }
  __syncthreads();
  if (t == 0) {
    ull picks[3];
    #pragma unroll
    for (int p = 0; p < 3; ++p) {
      ull bestk = ~0ull;
      for (int i = 0; i < 64; ++i) {
        const ull k = keys[i];
        if ((p > 0 && k == picks[0]) || (p > 1 && k == picks[1])) continue;
        bestk = umin64(bestk, k);
      }
      picks[p] = bestk;
      cand[(long)blockIdx.x * 3 + p] = bestk;
    }
  }
  __threadfence();
  __syncthreads();
  __shared__ unsigned rank_s;
  if (t == 0) rank_s = atomicAdd(&scal[9], 1u);
  __syncthreads();
  if (rank_s != NTOPB - 1) return;
  __threadfence();

  // last block: global first-min top-3 over candidates (matches lax.top_k ties)
  __shared__ ull shm[4];
  __shared__ ull picks_s[3];
  for (int p = 0; p < 3; ++p) {
    const ull e0 = (p > 0) ? picks_s[0] : 0ull;
    const ull e1 = (p > 1) ? picks_s[1] : 0ull;
    ull k = ~0ull;
    for (int n = t; n < NCAND; n += 256) {
      const ull c = cand[n];
      if ((p > 0 && c == e0) || (p > 1 && c == e1)) continue;
      k = umin64(k, c);
    }
    #pragma unroll
    for (int off = 1; off < 64; off <<= 1) k = umin64(k, shfl_xor_u64(k, off));
    if ((t & 63) == 0) shm[t >> 6] = k;
    __syncthreads();
    if (t == 0) {
      #pragma unroll
      for (int ww = 1; ww < 4; ++ww) k = umin64(k, shm[ww]);
      picks_s[p] = k;
    }
    __syncthreads();
  }
  // exact fp32 distances m_test vs the 2nd/3rd neighbors
  __shared__ float sh2[2];
  if (w < 2) {
    const unsigned nn = (unsigned)picks_s[1 + w];
    const float* mt2 = patch + (size_t)scal[0] * K_DIM;
    const float* pv  = lib + (size_t)nn * K_DIM;
    float s = 0.f;
    #pragma unroll
    for (int j = 0; j < 6; ++j) { const float d = mt2[lane + 64 * j] - pv[lane + 64 * j]; s += d * d; }
    #pragma unroll
    for (int m = 1; m < 64; m <<= 1) s += __shfl_xor(s, m, 64);
    if (lane == 0) sh2[w] = s;
  }
  __syncthreads();
  if (t == 0) {
    const float D = sqrtf((float)K_DIM);
    const float s_star = __uint_as_float(scal[1]);
    const float a = sqrtf(sh2[0]), b = sqrtf(sh2[1]);
    const float wgt = 1.f - expf(s_star / D) / (expf(a / D) + expf(b / D));
    out[0] = wgt * s_star;
  }
}

// ---------------- K5: fused bilinear 26->224 + separable 33-tap gaussian -----------------
static __device__ __forceinline__ int pc_refl(int i) {
  return i < 0 ? -i : (i >= IMG ? 2 * IMG - 2 - i : i);
}

__global__ void pc_map_kernel(const float* __restrict__ minval, float* __restrict__ outmap) {
  __shared__ double kd[KS + 1];
  __shared__ float kf[KS];
  __shared__ float smap[FMAP * FMAP];
  __shared__ float by[IMG];
  const int t = threadIdx.x;          // 256
  const int y = blockIdx.x;           // 224
  if (t < KS) { const double xx = (double)(t - KHALF) / 4.0; kd[t] = exp(-0.5 * xx * xx); }
  for (int i = t; i < FMAP * FMAP; i += 256) smap[i] = minval[i];
  __syncthreads();
  if (t == 0) { double s = 0.0; for (int i = 0; i < KS; ++i) s += kd[i]; kd[KS] = s; }
  __syncthreads();
  if (t < KS) kf[t] = (float)(kd[t] / kd[KS]);
  __syncthreads();

  const float scale = (float)FMAP / (float)IMG;
  if (t < IMG) {
    const float fx = ((float)t + 0.5f) * scale - 0.5f;
    const int ix0 = (int)floorf(fx); const float tx = fx - (float)ix0;
    const int x0 = min(max(ix0, 0), FMAP - 1), x1 = min(max(ix0 + 1, 0), FMAP - 1);
    float s = 0.f;
    #pragma unroll
    for (int j = 0; j < KS; ++j) {
      const int yy = pc_refl(y + j - KHALF);
      const float fy = ((float)yy + 0.5f) * scale - 0.5f;
      const int iy0 = (int)floorf(fy); const float ty = fy - (float)iy0;
      const int y0 = min(max(iy0, 0), FMAP - 1), y1 = min(max(iy0 + 1, 0), FMAP - 1);
      const float v00 = smap[y0 * FMAP + x0], v01 = smap[y0 * FMAP + x1];
      const float v10 = smap[y1 * FMAP + x0], v11 = smap[y1 * FMAP + x1];
      const float v0 = v00 + (v01 - v00) * tx;
      const float v1 = v10 + (v11 - v10) * tx;
      s += kf[j] * (v0 + (v1 - v0) * ty);
    }
    by[t] = s;
  }
  __syncthreads();
  if (t < IMG) {
    float s = 0.f;
    #pragma unroll
    for (int i = 0; i < KS; ++i) s += kf[i] * by[pc_refl(t + i - KHALF)];
    outmap[y * IMG + t] = s;
  }
}

extern "C" void kernel_launch(void* const* d_in, const int* in_sizes, int n_in,
                              void* d_out, int out_size, void* d_ws, size_t ws_size,
                              hipStream_t stream) {
  const float* patch = (const float*)d_in[0];
  const float* lib   = (const float*)d_in[1];
  float* out = (float*)d_out;

  char* p = (char*)d_ws;
  auto take = [&](size_t n) { char* q = p; p += (n + 511) & ~(size_t)511; return q; };
  float* y2        = (float*)take((size_t)N_PAD * 4);
  float* x2        = (float*)take((size_t)M_PAD * 4);
  ull* partial     = (ull*)take((size_t)(NCH + 2) * M_PAD * 8);   // +2 pad chunks
  ull* stage1      = (ull*)take((size_t)M_PAD * 8 * 8);
  float* minval    = (float*)take((size_t)M_PATCH * 4);
  unsigned* minidx = (unsigned*)take((size_t)M_PATCH * 4);
  unsigned* scal   = (unsigned*)take(256);                        // [0..7] results, [8..9] counters
  ull* cand        = (ull*)take((size_t)NCAND * 8);
  unsigned short* Afrag = (unsigned short*)take((size_t)NAG * 12 * 512 * 2);
  unsigned short* Bfrag = (unsigned short*)take((size_t)NBG * 12 * 512 * 2);
  (void)in_sizes; (void)n_in; (void)out_size; (void)ws_size;

  hipMemsetAsync(scal, 0, 64, stream);                                 // counters
  hipMemsetAsync(partial + (size_t)NCH * M_PAD, 0xFF, 2 * M_PAD * 8, stream);  // pad chunks -> +inf keys

  pc_cvt_kernel<<<NBG + NAG, 256, 0, stream>>>(patch, lib, y2, x2, Afrag, Bfrag);
  pc_gemm_min_kernel<<<GRID_GEMM, 256, 0, stream>>>(Afrag, Bfrag, x2, y2, partial);
  pc_reduce_kernel<<<48, 128, 0, stream>>>(partial, stage1, minval, minidx, scal);
  pc_wdist_kernel<<<NTOPB, 256, 0, stream>>>(patch, lib, scal, cand, out);
  pc_map_kernel<<<IMG, 256, 0, stream>>>(minval, out + 1);
}